// Round 3
// baseline (196.943 us; speedup 1.0000x reference)
//
#include <hip/hip_runtime.h>
#include <hip/hip_bf16.h>

#define B_ 4
#define T_ 2048
#define D_ 512

typedef __attribute__((ext_vector_type(8))) short short8;
typedef __attribute__((ext_vector_type(4))) short short4v;
typedef __attribute__((ext_vector_type(4))) float float4v;
typedef unsigned short bf16_t;

__device__ __forceinline__ bf16_t f2bf(float f) {
  unsigned int u = __builtin_bit_cast(unsigned int, f);
  unsigned int r = (u + 0x7fffu + ((u >> 16) & 1u)) >> 16;
  return (bf16_t)r;
}

__device__ __forceinline__ float waveReduceSum(float v) {
#pragma unroll
  for (int m = 32; m >= 1; m >>= 1) v += __shfl_xor(v, m, 64);
  return v;
}

// async global->LDS 16B: LDS dest = wave-uniform base + lane*16
__device__ __forceinline__ void gld16(const bf16_t* g, bf16_t* l) {
  __builtin_amdgcn_global_load_lds(
      (const __attribute__((address_space(1))) void*)g,
      (__attribute__((address_space(3))) void*)l, 16, 0, 0);
}

// ---------------- weight convert + transpose ----------------
// wqkvT[n][k] = w{q,k,v}[k][n] bf16; K rows pre-scaled by 1/8 (softmax scale)
__global__ __launch_bounds__(256) void wconv_kernel(
    const float* __restrict__ wq, const float* __restrict__ wk,
    const float* __restrict__ wv, const float* __restrict__ wfc,
    bf16_t* __restrict__ wqkvT, bf16_t* __restrict__ wfcT) {
  for (int idx = blockIdx.x * 256 + threadIdx.x; idx < 1048576; idx += 262144) {
    if (idx < 786432) {
      int n = idx >> 9, k = idx & 511;
      const float* src = (n < 512) ? wq : ((n < 1024) ? wk : wv);
      float scl = (n >= 512 && n < 1024) ? 0.125f : 1.0f;
      int c = n & 511;
      wqkvT[idx] = f2bf(src[k * 512 + c] * scl);
    } else {
      int j = idx - 786432;
      int n = j >> 9, k = j & 511;
      wfcT[j] = f2bf(wfc[k * 512 + n]);
    }
  }
}

// ---------------- LN1 + positional encoding ----------------
__global__ __launch_bounds__(256) void ln1_pe_kernel(
    const float* __restrict__ x, const float* __restrict__ g,
    const float* __restrict__ bb, float* __restrict__ h_f32,
    bf16_t* __restrict__ h_bf16) {
  int wave = threadIdx.x >> 6, lane = threadIdx.x & 63;
  int row = blockIdx.x * 4 + wave;
  int pos = row & (T_ - 1);
  const float* xr = x + (size_t)row * D_;
  int c0 = lane * 8;
  float v[8];
  float4 a = *(const float4*)(xr + c0);
  float4 b4 = *(const float4*)(xr + c0 + 4);
  v[0]=a.x; v[1]=a.y; v[2]=a.z; v[3]=a.w;
  v[4]=b4.x; v[5]=b4.y; v[6]=b4.z; v[7]=b4.w;
  float s = 0.f;
#pragma unroll
  for (int j = 0; j < 8; ++j) s += v[j];
  s = waveReduceSum(s);
  float mu = s * (1.f / 512.f);
  float q = 0.f;
#pragma unroll
  for (int j = 0; j < 8; ++j) { float d = v[j] - mu; q += d * d; }
  q = waveReduceSum(q);
  float rstd = rsqrtf(q * (1.f / 512.f) + 1e-5f);
  float* hr = h_f32 + (size_t)row * D_;
  bf16_t* hb = h_bf16 + (size_t)row * D_;
#pragma unroll
  for (int j = 0; j < 8; ++j) {
    int col = c0 + j;
    float hn = (v[j] - mu) * rstd * g[col] + bb[col];
    int i2 = (col >> 1) << 1;
    float dt = __expf((float)i2 * (-9.2103403719761836f / 512.0f));
    float ang = (float)pos * dt;
    float pe = (col & 1) ? __cosf(ang) : __sinf(ang);
    float hv = hn + pe;
    hr[col] = hv;
    hb[col] = f2bf(hv);
  }
}

// ---------------- 128x128 GEMM, global_load_lds + XOR swizzle ----------------
// C[M][N_COLS] = A[M][512] * Bt[N][512]^T
template <int N_COLS, int OUT_BF16>
__global__ __launch_bounds__(256) void gemm128_kernel(
    const bf16_t* __restrict__ A, const bf16_t* __restrict__ Bt,
    void* __restrict__ Cv) {
  __shared__ __align__(16) bf16_t As[128 * 64];
  __shared__ __align__(16) bf16_t Bs[128 * 64];
  const int m0 = blockIdx.y * 128, n0 = blockIdx.x * 128;
  const int tid = threadIdx.x;
  const int w = tid >> 6, lane = tid & 63;
  const int ln = lane & 15, quad = lane >> 4;
  const int wy = w >> 1, wx = w & 1;
  const int sw = ln & 7;

  float4v acc[4][4];
  float4v z = {0.f, 0.f, 0.f, 0.f};
#pragma unroll
  for (int i = 0; i < 4; ++i)
#pragma unroll
    for (int j = 0; j < 4; ++j) acc[i][j] = z;

  for (int k0 = 0; k0 < 512; k0 += 64) {
#pragma unroll
    for (int i = 0; i < 4; ++i) {
      int cbase = w * 256 + i * 64;
      int chunk = cbase + lane;
      int row = chunk >> 3;
      int lb = (chunk & 7) ^ (row & 7);  // swizzled logical 16B block
      gld16(A + (size_t)(m0 + row) * 512 + k0 + lb * 8, As + (size_t)cbase * 8);
      gld16(Bt + (size_t)(n0 + row) * 512 + k0 + lb * 8, Bs + (size_t)cbase * 8);
    }
    __syncthreads();
#pragma unroll
    for (int c = 0; c < 2; ++c) {
      short8 af[4], bf[4];
#pragma unroll
      for (int mt = 0; mt < 4; ++mt) {
        int row = wy * 64 + mt * 16 + ln;
        int pb = (c * 4 + quad) ^ sw;
        af[mt] = *(const short8*)(As + row * 64 + pb * 8);
      }
#pragma unroll
      for (int nt = 0; nt < 4; ++nt) {
        int row = wx * 64 + nt * 16 + ln;
        int pb = (c * 4 + quad) ^ sw;
        bf[nt] = *(const short8*)(Bs + row * 64 + pb * 8);
      }
#pragma unroll
      for (int mt = 0; mt < 4; ++mt)
#pragma unroll
        for (int nt = 0; nt < 4; ++nt)
          acc[mt][nt] = __builtin_amdgcn_mfma_f32_16x16x32_bf16(af[mt], bf[nt], acc[mt][nt], 0, 0, 0);
    }
    __syncthreads();
  }
#pragma unroll
  for (int mt = 0; mt < 4; ++mt)
#pragma unroll
    for (int r = 0; r < 4; ++r) {
      int row = m0 + wy * 64 + mt * 16 + quad * 4 + r;
#pragma unroll
      for (int nt = 0; nt < 4; ++nt) {
        int col = n0 + wx * 64 + nt * 16 + ln;
        if (OUT_BF16)
          ((bf16_t*)Cv)[(size_t)row * N_COLS + col] = f2bf(acc[mt][nt][r]);
        else
          ((float*)Cv)[(size_t)row * N_COLS + col] = acc[mt][nt][r];
      }
    }
}

// ---------------- flash-style causal attention (S^T formulation) ----------------
// qk: [B*T][1024] bf16 (Q | K(pre-scaled)), vT: [512][8192] bf16
__global__ __launch_bounds__(256) void attn_kernel(const bf16_t* __restrict__ qk,
                                                   const bf16_t* __restrict__ vT,
                                                   bf16_t* __restrict__ out) {
  __shared__ __align__(16) bf16_t Ks[2][64 * 64];
  __shared__ __align__(16) bf16_t Vs[2][64 * 64];
  __shared__ __align__(16) bf16_t Ps[4][16 * 72];
  const int bx = blockIdx.x;
  const int qt = 31 - (bx >> 5);      // long blocks first
  const int bh = bx & 31;
  const int b = bh >> 3, h = bh & 7;
  const int tid = threadIdx.x;
  const int w = tid >> 6, lane = tid & 63;
  const int ln = lane & 15, quad = lane >> 4;
  const int sw = ln & 7;

  short8 qf0, qf1;
  {
    size_t qrow = ((size_t)b * T_ + qt * 64 + w * 16 + ln) * 1024 + h * 64;
    qf0 = *(const short8*)(qk + qrow + quad * 8);
    qf1 = *(const short8*)(qk + qrow + 32 + quad * 8);
  }
  float4v z = {0.f, 0.f, 0.f, 0.f};
  float4v oacc[4];
#pragma unroll
  for (int i = 0; i < 4; ++i) oacc[i] = z;
  float m_s = -1e30f, l_s = 0.f;

  const bf16_t* kbase = qk + (size_t)b * T_ * 1024 + 512 + h * 64;
  const bf16_t* vbase = vT + (size_t)(h * 64) * 8192 + (size_t)b * T_;
  bf16_t* Psw = Ps[w];

  auto stage = [&](int buf, int kt) {
#pragma unroll
    for (int i = 0; i < 2; ++i) {
      int cbase = w * 128 + i * 64;
      int chunk = cbase + lane;
      int row = chunk >> 3;
      int lb = (chunk & 7) ^ (row & 7);
      gld16(kbase + (size_t)(kt * 64 + row) * 1024 + lb * 8, Ks[buf] + (size_t)cbase * 8);
      gld16(vbase + (size_t)row * 8192 + kt * 64 + lb * 8, Vs[buf] + (size_t)cbase * 8);
    }
  };

  auto compute = [&](const bf16_t* Kc, const bf16_t* Vc, bool mask) {
    float sv[4][4];
#pragma unroll
    for (int mt = 0; mt < 4; ++mt) {
      float4v st = z;
      int row = mt * 16 + ln;
      short8 a0 = *(const short8*)(Kc + row * 64 + ((0 + quad) ^ sw) * 8);
      short8 a1 = *(const short8*)(Kc + row * 64 + ((4 + quad) ^ sw) * 8);
      st = __builtin_amdgcn_mfma_f32_16x16x32_bf16(a0, qf0, st, 0, 0, 0);
      st = __builtin_amdgcn_mfma_f32_16x16x32_bf16(a1, qf1, st, 0, 0, 0);
#pragma unroll
      for (int r = 0; r < 4; ++r) {
        float v = st[r];
        if (mask) {
          int kloc = mt * 16 + quad * 4 + r;
          if (kloc > w * 16 + ln) v = -1e30f;
        }
        sv[mt][r] = v;
      }
    }
    float mx = sv[0][0];
#pragma unroll
    for (int mt = 0; mt < 4; ++mt)
#pragma unroll
      for (int r = 0; r < 4; ++r) mx = fmaxf(mx, sv[mt][r]);
    mx = fmaxf(mx, __shfl_xor(mx, 16, 64));
    mx = fmaxf(mx, __shfl_xor(mx, 32, 64));
    float mn = fmaxf(m_s, mx);
    float alpha = __expf(m_s - mn);
    m_s = mn;
    float rs = 0.f;
#pragma unroll
    for (int mt = 0; mt < 4; ++mt)
#pragma unroll
      for (int r = 0; r < 4; ++r) {
        float p = __expf(sv[mt][r] - mn);
        sv[mt][r] = p;
        rs += p;
      }
    rs += __shfl_xor(rs, 16, 64);
    rs += __shfl_xor(rs, 32, 64);
    l_s = l_s * alpha + rs;
#pragma unroll
    for (int dt = 0; dt < 4; ++dt)
#pragma unroll
      for (int r = 0; r < 4; ++r) oacc[dt][r] *= alpha;
#pragma unroll
    for (int mt = 0; mt < 4; ++mt) {
      short4v p4;
#pragma unroll
      for (int r = 0; r < 4; ++r) p4[r] = (short)f2bf(sv[mt][r]);
      *(short4v*)(Psw + ln * 72 + mt * 16 + quad * 4) = p4;
    }
    short8 bp0 = *(short8*)(Psw + ln * 72 + quad * 8);
    short8 bp1 = *(short8*)(Psw + ln * 72 + 32 + quad * 8);
#pragma unroll
    for (int dt = 0; dt < 4; ++dt) {
      int row = dt * 16 + ln;
      short8 av0 = *(const short8*)(Vc + row * 64 + ((0 + quad) ^ sw) * 8);
      short8 av1 = *(const short8*)(Vc + row * 64 + ((4 + quad) ^ sw) * 8);
      oacc[dt] = __builtin_amdgcn_mfma_f32_16x16x32_bf16(av0, bp0, oacc[dt], 0, 0, 0);
      oacc[dt] = __builtin_amdgcn_mfma_f32_16x16x32_bf16(av1, bp1, oacc[dt], 0, 0, 0);
    }
  };

  stage(0, 0);
  __syncthreads();
  for (int kt = 0; kt < qt; ++kt) {
    int cur = kt & 1;
    stage(cur ^ 1, kt + 1);          // async prefetch, drained by barrier below
    compute(Ks[cur], Vs[cur], false);
    __syncthreads();
  }
  compute(Ks[qt & 1], Vs[qt & 1], true);  // peeled masked diagonal tile

  float inv = 1.0f / l_s;
  size_t obase = ((size_t)b * T_ + qt * 64 + w * 16 + ln) * 512 + h * 64;
#pragma unroll
  for (int dt = 0; dt < 4; ++dt) {
    short4v o4;
#pragma unroll
    for (int r = 0; r < 4; ++r) o4[r] = (short)f2bf(oacc[dt][r] * inv);
    *(short4v*)(out + obase + dt * 16 + quad * 4) = o4;
  }
}

// ---------------- final LN + residuals ----------------
__global__ __launch_bounds__(256) void ln2_kernel(
    const float* __restrict__ o2, const float* __restrict__ hres,
    const float* __restrict__ x, const float* __restrict__ g,
    const float* __restrict__ bb, float* __restrict__ out) {
  int wave = threadIdx.x >> 6, lane = threadIdx.x & 63;
  int row = blockIdx.x * 4 + wave;
  size_t ro = (size_t)row * D_;
  int c0 = lane * 8;
  float t[8];
  float4 a0 = *(const float4*)(o2 + ro + c0);
  float4 a1 = *(const float4*)(o2 + ro + c0 + 4);
  float4 h0 = *(const float4*)(hres + ro + c0);
  float4 h1 = *(const float4*)(hres + ro + c0 + 4);
  t[0]=a0.x+h0.x; t[1]=a0.y+h0.y; t[2]=a0.z+h0.z; t[3]=a0.w+h0.w;
  t[4]=a1.x+h1.x; t[5]=a1.y+h1.y; t[6]=a1.z+h1.z; t[7]=a1.w+h1.w;
  float s = 0.f;
#pragma unroll
  for (int j = 0; j < 8; ++j) s += t[j];
  s = waveReduceSum(s);
  float mu = s * (1.f / 512.f);
  float q = 0.f;
#pragma unroll
  for (int j = 0; j < 8; ++j) { float d = t[j] - mu; q += d * d; }
  q = waveReduceSum(q);
  float rstd = rsqrtf(q * (1.f / 512.f) + 1e-6f);
#pragma unroll
  for (int j = 0; j < 8; ++j) {
    int col = c0 + j;
    out[ro + col] = (t[j] - mu) * rstd * g[col] + bb[col] + x[ro + col];
  }
}

// ---------------- launch ----------------
extern "C" void kernel_launch(void* const* d_in, const int* in_sizes, int n_in,
                              void* d_out, int out_size, void* d_ws, size_t ws_size,
                              hipStream_t stream) {
  const float* x   = (const float*)d_in[0];
  const float* g1  = (const float*)d_in[1];
  const float* b1  = (const float*)d_in[2];
  const float* wq  = (const float*)d_in[3];
  const float* wk  = (const float*)d_in[4];
  const float* wv  = (const float*)d_in[5];
  const float* wfc = (const float*)d_in[6];
  const float* g2  = (const float*)d_in[7];
  const float* b2  = (const float*)d_in[8];
  float* out = (float*)d_out;

  char* ws = (char*)d_ws;
  const size_t O_HF32  = 0;                  // 8192*512*4
  const size_t O_HBF   = 16777216;           // 8192*512*2
  const size_t O_WQKV  = 25165824;           // 1536*512*2
  const size_t O_WFC   = 26738688;           //  512*512*2
  const size_t O_QK    = 27262976;           // 8192*1024*2
  const size_t O_VT    = 44040192;           //  512*8192*2
  const size_t O_ATTN  = 52428800;           // 8192*512*2
  const size_t O_O2    = 60817408;           // 8192*512*4
  const size_t WS_NEED = 77594624;
  if (ws_size < WS_NEED) return;

  float*  h_f32 = (float*)(ws + O_HF32);
  bf16_t* h_bf  = (bf16_t*)(ws + O_HBF);
  bf16_t* wqkvT = (bf16_t*)(ws + O_WQKV);
  bf16_t* wfcT  = (bf16_t*)(ws + O_WFC);
  bf16_t* qk    = (bf16_t*)(ws + O_QK);
  bf16_t* vT    = (bf16_t*)(ws + O_VT);
  bf16_t* attn  = (bf16_t*)(ws + O_ATTN);
  float*  o2    = (float*)(ws + O_O2);

  wconv_kernel<<<dim3(1024), dim3(256), 0, stream>>>(wq, wk, wv, wfc, wqkvT, wfcT);
  ln1_pe_kernel<<<dim3(2048), dim3(256), 0, stream>>>(x, g1, b1, h_f32, h_bf);
  // Q|K projection: [8192][1024]
  gemm128_kernel<1024, 1><<<dim3(8, 64), dim3(256), 0, stream>>>(h_bf, wqkvT, (void*)qk);
  // V^T projection: [512][8192]
  gemm128_kernel<8192, 1><<<dim3(64, 4), dim3(256), 0, stream>>>(wqkvT + 1024 * 512, h_bf, (void*)vT);
  attn_kernel<<<dim3(1024), dim3(256), 0, stream>>>(qk, vT, attn);
  // output projection: [8192][512] f32
  gemm128_kernel<512, 0><<<dim3(4, 64), dim3(256), 0, stream>>>(attn, wfcT, (void*)o2);
  ln2_kernel<<<dim3(2048), dim3(256), 0, stream>>>(o2, h_f32, x, g2, b2, out);
}

// Round 6
// 196.024 us; speedup vs baseline: 1.0047x; 1.0047x over previous
//
#include <hip/hip_runtime.h>
#include <hip/hip_bf16.h>

#define B_ 4
#define T_ 2048
#define D_ 512

typedef __attribute__((ext_vector_type(8))) short short8;
typedef __attribute__((ext_vector_type(4))) short short4v;
typedef __attribute__((ext_vector_type(4))) float float4v;
typedef unsigned short bf16_t;

__device__ __forceinline__ bf16_t f2bf(float f) {
  unsigned int u = __builtin_bit_cast(unsigned int, f);
  unsigned int r = (u + 0x7fffu + ((u >> 16) & 1u)) >> 16;
  return (bf16_t)r;
}
__device__ __forceinline__ float bf2f(bf16_t b) {
  unsigned int u = ((unsigned int)b) << 16;
  return __builtin_bit_cast(float, u);
}

__device__ __forceinline__ float waveReduceSum(float v) {
#pragma unroll
  for (int m = 32; m >= 1; m >>= 1) v += __shfl_xor(v, m, 64);
  return v;
}

// async global->LDS 16B: LDS dest = wave-uniform base + lane*16
__device__ __forceinline__ void gld16(const bf16_t* g, bf16_t* l) {
  __builtin_amdgcn_global_load_lds(
      (const __attribute__((address_space(1))) void*)g,
      (__attribute__((address_space(3))) void*)l, 16, 0, 0);
}

// ---------------- fused: weight convert/transpose + LN1+PE ----------------
// blocks [0,2048): LN1+PE over 4 rows each -> h_bf
// blocks [2048,2304): weight transpose (K rows pre-scaled by 1/8)
__global__ __launch_bounds__(256) void pre_kernel(
    const float* __restrict__ x, const float* __restrict__ g,
    const float* __restrict__ bb,
    const float* __restrict__ wq, const float* __restrict__ wk,
    const float* __restrict__ wv, const float* __restrict__ wfc,
    bf16_t* __restrict__ h_bf16,
    bf16_t* __restrict__ wqkvT, bf16_t* __restrict__ wfcT) {
  if (blockIdx.x >= 2048) {
    int bid = blockIdx.x - 2048;
#pragma unroll 4
    for (int i = 0; i < 16; ++i) {
      int idx = bid * 4096 + i * 256 + threadIdx.x;
      if (idx < 786432) {
        int n = idx >> 9, k = idx & 511;
        const float* src = (n < 512) ? wq : ((n < 1024) ? wk : wv);
        float scl = (n >= 512 && n < 1024) ? 0.125f : 1.0f;
        int c = n & 511;
        wqkvT[idx] = f2bf(src[k * 512 + c] * scl);
      } else {
        int j = idx - 786432;
        int n = j >> 9, k = j & 511;
        wfcT[j] = f2bf(wfc[k * 512 + n]);
      }
    }
    return;
  }
  int wave = threadIdx.x >> 6, lane = threadIdx.x & 63;
  int row = blockIdx.x * 4 + wave;
  int pos = row & (T_ - 1);
  const float* xr = x + (size_t)row * D_;
  int c0 = lane * 8;
  float v[8];
  float4 a = *(const float4*)(xr + c0);
  float4 b4 = *(const float4*)(xr + c0 + 4);
  v[0]=a.x; v[1]=a.y; v[2]=a.z; v[3]=a.w;
  v[4]=b4.x; v[5]=b4.y; v[6]=b4.z; v[7]=b4.w;
  float s = 0.f;
#pragma unroll
  for (int j = 0; j < 8; ++j) s += v[j];
  s = waveReduceSum(s);
  float mu = s * (1.f / 512.f);
  float q = 0.f;
#pragma unroll
  for (int j = 0; j < 8; ++j) { float d = v[j] - mu; q += d * d; }
  q = waveReduceSum(q);
  float rstd = rsqrtf(q * (1.f / 512.f) + 1e-5f);
  bf16_t* hb = h_bf16 + (size_t)row * D_;
#pragma unroll
  for (int j = 0; j < 8; ++j) {
    int col = c0 + j;
    float hn = (v[j] - mu) * rstd * g[col] + bb[col];
    int i2 = (col >> 1) << 1;
    float dt = __expf((float)i2 * (-9.2103403719761836f / 512.0f));
    float ang = (float)pos * dt;
    float pe = (col & 1) ? __cosf(ang) : __sinf(ang);
    hb[col] = f2bf(hn + pe);
  }
}

// ---------------- shared 128x128 dbuf GEMM body ----------------
template <typename EPI>
__device__ __forceinline__ void gemm_body(const bf16_t* __restrict__ A,
                                          const bf16_t* __restrict__ Bt,
                                          int m0, int n0, bf16_t* As, bf16_t* Bs,
                                          EPI epi) {
  const int tid = threadIdx.x;
  const int w = tid >> 6, lane = tid & 63;
  const int ln = lane & 15, quad = lane >> 4;
  const int wy = w >> 1, wx = w & 1;
  const int sw = ln & 7;

  float4v acc[4][4];
  float4v z = {0.f, 0.f, 0.f, 0.f};
#pragma unroll
  for (int i = 0; i < 4; ++i)
#pragma unroll
    for (int j = 0; j < 4; ++j) acc[i][j] = z;

  auto stage = [&](int buf, int k0) {
#pragma unroll
    for (int i = 0; i < 4; ++i) {
      int cbase = w * 256 + i * 64;
      int chunk = cbase + lane;
      int row = chunk >> 3;
      int lb = (chunk & 7) ^ (row & 7);
      // per-buffer stride is 8192 ELEMENTS; cbase is in 64-elem chunks (x8)
      gld16(A + (size_t)(m0 + row) * 512 + k0 + lb * 8, As + buf * 8192 + cbase * 8);
      gld16(Bt + (size_t)(n0 + row) * 512 + k0 + lb * 8, Bs + buf * 8192 + cbase * 8);
    }
  };

  stage(0, 0);
  __syncthreads();
  for (int kb = 0; kb < 8; ++kb) {
    int cur = kb & 1;
    if (kb < 7) stage(cur ^ 1, (kb + 1) * 64);
    const bf16_t* Ac = As + cur * 8192;
    const bf16_t* Bc = Bs + cur * 8192;
#pragma unroll
    for (int c = 0; c < 2; ++c) {
      short8 af[4], bf[4];
#pragma unroll
      for (int mt = 0; mt < 4; ++mt)
        af[mt] = *(const short8*)(Ac + (wy * 64 + mt * 16 + ln) * 64 + (((c * 4 + quad) ^ sw)) * 8);
#pragma unroll
      for (int nt = 0; nt < 4; ++nt)
        bf[nt] = *(const short8*)(Bc + (wx * 64 + nt * 16 + ln) * 64 + (((c * 4 + quad) ^ sw)) * 8);
#pragma unroll
      for (int mt = 0; mt < 4; ++mt)
#pragma unroll
        for (int nt = 0; nt < 4; ++nt)
          acc[mt][nt] = __builtin_amdgcn_mfma_f32_16x16x32_bf16(af[mt], bf[nt], acc[mt][nt], 0, 0, 0);
    }
    __syncthreads();
  }
#pragma unroll
  for (int mt = 0; mt < 4; ++mt)
#pragma unroll
    for (int r = 0; r < 4; ++r) {
      int row = m0 + wy * 64 + mt * 16 + quad * 4 + r;
#pragma unroll
      for (int nt = 0; nt < 4; ++nt) {
        int col = n0 + wx * 64 + nt * 16 + ln;
        epi(row, col, acc[mt][nt][r]);
      }
    }
}

// blocks [0,512): QK proj -> qk[8192][1024]; [512,768): V^T -> vT[512][8192]
__global__ __launch_bounds__(256) void gemm_qkvt_kernel(
    const bf16_t* __restrict__ h_bf, const bf16_t* __restrict__ wqkvT,
    bf16_t* __restrict__ qk, bf16_t* __restrict__ vT) {
  __shared__ __align__(16) bf16_t As[2 * 128 * 64];
  __shared__ __align__(16) bf16_t Bs[2 * 128 * 64];
  int bx = blockIdx.x;
  if (bx < 512) {
    int m0 = (bx >> 3) * 128, n0 = (bx & 7) * 128;
    gemm_body(h_bf, wqkvT, m0, n0, As, Bs,
              [&](int row, int col, float v) { qk[(size_t)row * 1024 + col] = f2bf(v); });
  } else {
    int local = bx - 512;
    int m0 = (local >> 6) * 128, n0 = (local & 63) * 128;
    gemm_body(wqkvT + 1024 * 512, h_bf, m0, n0, As, Bs,
              [&](int row, int col, float v) { vT[(size_t)row * 8192 + col] = f2bf(v); });
  }
}

// out-proj GEMM + residual (h_bf) epilogue -> o2r bf16 [8192][512]
__global__ __launch_bounds__(256) void gemm_out_kernel(
    const bf16_t* __restrict__ attn, const bf16_t* __restrict__ wfcT,
    const bf16_t* __restrict__ h_bf, bf16_t* __restrict__ o2r) {
  __shared__ __align__(16) bf16_t As[2 * 128 * 64];
  __shared__ __align__(16) bf16_t Bs[2 * 128 * 64];
  int bx = blockIdx.x;
  int m0 = (bx >> 2) * 128, n0 = (bx & 3) * 128;
  gemm_body(attn, wfcT, m0, n0, As, Bs, [&](int row, int col, float v) {
    size_t o = (size_t)row * 512 + col;
    o2r[o] = f2bf(v + bf2f(h_bf[o]));
  });
}

// ---------------- flash-style causal attention (S^T formulation) ----------------
// qk: [B*T][1024] bf16 (Q | K pre-scaled), vT: [512][8192] bf16
// PV via r3-verified Ps LDS round-trip (wave-private, no barrier)
__global__ __launch_bounds__(256) void attn_kernel(const bf16_t* __restrict__ qk,
                                                   const bf16_t* __restrict__ vT,
                                                   bf16_t* __restrict__ out) {
  __shared__ __align__(16) bf16_t Ks[2][64 * 64];
  __shared__ __align__(16) bf16_t Vs[2][64 * 64];
  __shared__ __align__(16) bf16_t Ps[4][16 * 72];
  const int bx = blockIdx.x;
  const int qt = 31 - (bx >> 5);      // long blocks first
  const int bh = bx & 31;
  const int b = bh >> 3, h = bh & 7;
  const int tid = threadIdx.x;
  const int w = tid >> 6, lane = tid & 63;
  const int ln = lane & 15, quad = lane >> 4;
  const int sw = ln & 7;

  short8 qf0, qf1;
  {
    size_t qrow = ((size_t)b * T_ + qt * 64 + w * 16 + ln) * 1024 + h * 64;
    qf0 = *(const short8*)(qk + qrow + quad * 8);
    qf1 = *(const short8*)(qk + qrow + 32 + quad * 8);
  }
  float4v z = {0.f, 0.f, 0.f, 0.f};
  float4v oacc[4];
#pragma unroll
  for (int i = 0; i < 4; ++i) oacc[i] = z;
  float m_s = -1e30f, l_s = 0.f;

  const bf16_t* kbase = qk + (size_t)b * T_ * 1024 + 512 + h * 64;
  const bf16_t* vbase = vT + (size_t)(h * 64) * 8192 + (size_t)b * T_;
  bf16_t* Psw = Ps[w];

  auto stage = [&](int buf, int kt) {
#pragma unroll
    for (int i = 0; i < 2; ++i) {
      int cbase = w * 128 + i * 64;
      int chunk = cbase + lane;
      int row = chunk >> 3;
      int lb = (chunk & 7) ^ (row & 7);
      gld16(kbase + (size_t)(kt * 64 + row) * 1024 + lb * 8, Ks[buf] + (size_t)cbase * 8);
      gld16(vbase + (size_t)row * 8192 + kt * 64 + lb * 8, Vs[buf] + (size_t)cbase * 8);
    }
  };

  auto compute = [&](const bf16_t* Kc, const bf16_t* Vc, bool mask) {
    float sv[4][4];
#pragma unroll
    for (int mt = 0; mt < 4; ++mt) {
      float4v st = z;
      int row = mt * 16 + ln;
      short8 a0 = *(const short8*)(Kc + row * 64 + ((0 + quad) ^ sw) * 8);
      short8 a1 = *(const short8*)(Kc + row * 64 + ((4 + quad) ^ sw) * 8);
      st = __builtin_amdgcn_mfma_f32_16x16x32_bf16(a0, qf0, st, 0, 0, 0);
      st = __builtin_amdgcn_mfma_f32_16x16x32_bf16(a1, qf1, st, 0, 0, 0);
#pragma unroll
      for (int r = 0; r < 4; ++r) {
        float v = st[r];
        if (mask) {
          int kloc = mt * 16 + quad * 4 + r;
          if (kloc > w * 16 + ln) v = -1e30f;
        }
        sv[mt][r] = v;
      }
    }
    float mx = sv[0][0];
#pragma unroll
    for (int mt = 0; mt < 4; ++mt)
#pragma unroll
      for (int r = 0; r < 4; ++r) mx = fmaxf(mx, sv[mt][r]);
    mx = fmaxf(mx, __shfl_xor(mx, 16, 64));
    mx = fmaxf(mx, __shfl_xor(mx, 32, 64));
    float mn = fmaxf(m_s, mx);
    float alpha = __expf(m_s - mn);
    m_s = mn;
    float rs = 0.f;
#pragma unroll
    for (int mt = 0; mt < 4; ++mt)
#pragma unroll
      for (int r = 0; r < 4; ++r) {
        float p = __expf(sv[mt][r] - mn);
        sv[mt][r] = p;
        rs += p;
      }
    rs += __shfl_xor(rs, 16, 64);
    rs += __shfl_xor(rs, 32, 64);
    l_s = l_s * alpha + rs;
#pragma unroll
    for (int dt = 0; dt < 4; ++dt)
#pragma unroll
      for (int r = 0; r < 4; ++r) oacc[dt][r] *= alpha;
    // P -> Ps (wave-private, same-wave rows; lgkmcnt orders write->read)
#pragma unroll
    for (int mt = 0; mt < 4; ++mt) {
      short4v p4;
#pragma unroll
      for (int r = 0; r < 4; ++r) p4[r] = (short)f2bf(sv[mt][r]);
      *(short4v*)(Psw + ln * 72 + mt * 16 + quad * 4) = p4;
    }
    short8 bp0 = *(short8*)(Psw + ln * 72 + quad * 8);
    short8 bp1 = *(short8*)(Psw + ln * 72 + 32 + quad * 8);
#pragma unroll
    for (int dt = 0; dt < 4; ++dt) {
      int row = dt * 16 + ln;
      short8 av0 = *(const short8*)(Vc + row * 64 + ((0 + quad) ^ sw) * 8);
      short8 av1 = *(const short8*)(Vc + row * 64 + ((4 + quad) ^ sw) * 8);
      oacc[dt] = __builtin_amdgcn_mfma_f32_16x16x32_bf16(av0, bp0, oacc[dt], 0, 0, 0);
      oacc[dt] = __builtin_amdgcn_mfma_f32_16x16x32_bf16(av1, bp1, oacc[dt], 0, 0, 0);
    }
  };

  stage(0, 0);
  __syncthreads();
  for (int kt = 0; kt < qt; ++kt) {
    int cur = kt & 1;
    stage(cur ^ 1, kt + 1);
    compute(Ks[cur], Vs[cur], false);
    __syncthreads();
  }
  compute(Ks[qt & 1], Vs[qt & 1], true);

  float inv = 1.0f / l_s;
  size_t obase = ((size_t)b * T_ + qt * 64 + w * 16 + ln) * 512 + h * 64;
#pragma unroll
  for (int dt = 0; dt < 4; ++dt) {
    short4v o4;
#pragma unroll
    for (int r = 0; r < 4; ++r) o4[r] = (short)f2bf(oacc[dt][r] * inv);
    *(short4v*)(out + obase + dt * 16 + quad * 4) = o4;
  }
}

// ---------------- final LN + residual ----------------
__global__ __launch_bounds__(256) void ln2_kernel(
    const bf16_t* __restrict__ o2r, const float* __restrict__ x,
    const float* __restrict__ g, const float* __restrict__ bb,
    float* __restrict__ out) {
  int wave = threadIdx.x >> 6, lane = threadIdx.x & 63;
  int row = blockIdx.x * 4 + wave;
  size_t ro = (size_t)row * D_;
  int c0 = lane * 8;
  short8 ov = *(const short8*)(o2r + ro + c0);
  float t[8];
#pragma unroll
  for (int j = 0; j < 8; ++j) t[j] = bf2f((bf16_t)ov[j]);
  float s = 0.f;
#pragma unroll
  for (int j = 0; j < 8; ++j) s += t[j];
  s = waveReduceSum(s);
  float mu = s * (1.f / 512.f);
  float q = 0.f;
#pragma unroll
  for (int j = 0; j < 8; ++j) { float d = t[j] - mu; q += d * d; }
  q = waveReduceSum(q);
  float rstd = rsqrtf(q * (1.f / 512.f) + 1e-6f);
  float4 x0 = *(const float4*)(x + ro + c0);
  float4 x1 = *(const float4*)(x + ro + c0 + 4);
  float xr[8] = {x0.x, x0.y, x0.z, x0.w, x1.x, x1.y, x1.z, x1.w};
  float o[8];
#pragma unroll
  for (int j = 0; j < 8; ++j) {
    int col = c0 + j;
    o[j] = (t[j] - mu) * rstd * g[col] + bb[col] + xr[j];
  }
  float4 w0 = {o[0], o[1], o[2], o[3]};
  float4 w1 = {o[4], o[5], o[6], o[7]};
  *(float4*)(out + ro + c0) = w0;
  *(float4*)(out + ro + c0 + 4) = w1;
}

// ---------------- launch ----------------
extern "C" void kernel_launch(void* const* d_in, const int* in_sizes, int n_in,
                              void* d_out, int out_size, void* d_ws, size_t ws_size,
                              hipStream_t stream) {
  const float* x   = (const float*)d_in[0];
  const float* g1  = (const float*)d_in[1];
  const float* b1  = (const float*)d_in[2];
  const float* wq  = (const float*)d_in[3];
  const float* wk  = (const float*)d_in[4];
  const float* wv  = (const float*)d_in[5];
  const float* wfc = (const float*)d_in[6];
  const float* g2  = (const float*)d_in[7];
  const float* b2  = (const float*)d_in[8];
  float* out = (float*)d_out;

  char* ws = (char*)d_ws;
  const size_t O_HBF  = 0;          // 8192*512*2  =  8388608
  const size_t O_WQKV = 8388608;    // 1536*512*2  =  1572864
  const size_t O_WFC  = 9961472;    //  512*512*2  =   524288
  const size_t O_QK   = 10485760;   // 8192*1024*2 = 16777216
  const size_t O_VT   = 27262976;   //  512*8192*2 =  8388608
  const size_t O_ATTN = 35651584;   // 8192*512*2  =  8388608
  const size_t O_O2R  = 44040192;   // 8192*512*2  =  8388608
  const size_t WS_NEED = 52428800;
  if (ws_size < WS_NEED) return;

  bf16_t* h_bf  = (bf16_t*)(ws + O_HBF);
  bf16_t* wqkvT = (bf16_t*)(ws + O_WQKV);
  bf16_t* wfcT  = (bf16_t*)(ws + O_WFC);
  bf16_t* qk    = (bf16_t*)(ws + O_QK);
  bf16_t* vT    = (bf16_t*)(ws + O_VT);
  bf16_t* attn  = (bf16_t*)(ws + O_ATTN);
  bf16_t* o2r   = (bf16_t*)(ws + O_O2R);

  pre_kernel<<<dim3(2304), dim3(256), 0, stream>>>(x, g1, b1, wq, wk, wv, wfc,
                                                   h_bf, wqkvT, wfcT);
  gemm_qkvt_kernel<<<dim3(768), dim3(256), 0, stream>>>(h_bf, wqkvT, qk, vT);
  attn_kernel<<<dim3(1024), dim3(256), 0, stream>>>(qk, vT, attn);
  gemm_out_kernel<<<dim3(256), dim3(256), 0, stream>>>(attn, wfcT, h_bf, o2r);
  ln2_kernel<<<dim3(2048), dim3(256), 0, stream>>>(o2r, x, g2, b2, out);
}

// Round 7
// 185.720 us; speedup vs baseline: 1.0604x; 1.0555x over previous
//
#include <hip/hip_runtime.h>
#include <hip/hip_bf16.h>

#define B_ 4
#define T_ 2048
#define D_ 512

typedef __attribute__((ext_vector_type(8))) short short8;
typedef __attribute__((ext_vector_type(4))) short short4v;
typedef __attribute__((ext_vector_type(4))) float float4v;
typedef unsigned short bf16_t;

__device__ __forceinline__ bf16_t f2bf(float f) {
  unsigned int u = __builtin_bit_cast(unsigned int, f);
  unsigned int r = (u + 0x7fffu + ((u >> 16) & 1u)) >> 16;
  return (bf16_t)r;
}
__device__ __forceinline__ float bf2f(bf16_t b) {
  unsigned int u = ((unsigned int)b) << 16;
  return __builtin_bit_cast(float, u);
}

__device__ __forceinline__ float waveReduceSum(float v) {
#pragma unroll
  for (int m = 32; m >= 1; m >>= 1) v += __shfl_xor(v, m, 64);
  return v;
}

// async global->LDS 16B: LDS dest = wave-uniform base + lane*16
__device__ __forceinline__ void gld16(const bf16_t* g, bf16_t* l) {
  __builtin_amdgcn_global_load_lds(
      (const __attribute__((address_space(1))) void*)g,
      (__attribute__((address_space(3))) void*)l, 16, 0, 0);
}

// ---------------- fused: weight convert/transpose + LN1+PE ----------------
__global__ __launch_bounds__(256) void pre_kernel(
    const float* __restrict__ x, const float* __restrict__ g,
    const float* __restrict__ bb,
    const float* __restrict__ wq, const float* __restrict__ wk,
    const float* __restrict__ wv, const float* __restrict__ wfc,
    bf16_t* __restrict__ h_bf16,
    bf16_t* __restrict__ wqkvT, bf16_t* __restrict__ wfcT) {
  if (blockIdx.x >= 2048) {
    int bid = blockIdx.x - 2048;
#pragma unroll 4
    for (int i = 0; i < 16; ++i) {
      int idx = bid * 4096 + i * 256 + threadIdx.x;
      if (idx < 786432) {
        int n = idx >> 9, k = idx & 511;
        const float* src = (n < 512) ? wq : ((n < 1024) ? wk : wv);
        float scl = (n >= 512 && n < 1024) ? 0.125f : 1.0f;
        int c = n & 511;
        wqkvT[idx] = f2bf(src[k * 512 + c] * scl);
      } else {
        int j = idx - 786432;
        int n = j >> 9, k = j & 511;
        wfcT[j] = f2bf(wfc[k * 512 + n]);
      }
    }
    return;
  }
  int wave = threadIdx.x >> 6, lane = threadIdx.x & 63;
  int row = blockIdx.x * 4 + wave;
  int pos = row & (T_ - 1);
  const float* xr = x + (size_t)row * D_;
  int c0 = lane * 8;
  float v[8];
  float4 a = *(const float4*)(xr + c0);
  float4 b4 = *(const float4*)(xr + c0 + 4);
  v[0]=a.x; v[1]=a.y; v[2]=a.z; v[3]=a.w;
  v[4]=b4.x; v[5]=b4.y; v[6]=b4.z; v[7]=b4.w;
  float s = 0.f;
#pragma unroll
  for (int j = 0; j < 8; ++j) s += v[j];
  s = waveReduceSum(s);
  float mu = s * (1.f / 512.f);
  float q = 0.f;
#pragma unroll
  for (int j = 0; j < 8; ++j) { float d = v[j] - mu; q += d * d; }
  q = waveReduceSum(q);
  float rstd = rsqrtf(q * (1.f / 512.f) + 1e-5f);
  bf16_t* hb = h_bf16 + (size_t)row * D_;
#pragma unroll
  for (int j = 0; j < 8; ++j) {
    int col = c0 + j;
    float hn = (v[j] - mu) * rstd * g[col] + bb[col];
    int i2 = (col >> 1) << 1;
    float dt = __expf((float)i2 * (-9.2103403719761836f / 512.0f));
    float ang = (float)pos * dt;
    float pe = (col & 1) ? __cosf(ang) : __sinf(ang);
    hb[col] = f2bf(hn + pe);
  }
}

// ---------------- 128x128 GEMM, single-buffer m97 structure (32 KB LDS) ----------------
template <typename EPI>
__device__ __forceinline__ void gemm_body(const bf16_t* __restrict__ A,
                                          const bf16_t* __restrict__ Bt,
                                          int m0, int n0, bf16_t* As, bf16_t* Bs,
                                          EPI epi) {
  const int tid = threadIdx.x;
  const int w = tid >> 6, lane = tid & 63;
  const int ln = lane & 15, quad = lane >> 4;
  const int wy = w >> 1, wx = w & 1;
  const int sw = ln & 7;

  float4v acc[4][4];
  float4v z = {0.f, 0.f, 0.f, 0.f};
#pragma unroll
  for (int i = 0; i < 4; ++i)
#pragma unroll
    for (int j = 0; j < 4; ++j) acc[i][j] = z;

  for (int k0 = 0; k0 < 512; k0 += 64) {
#pragma unroll
    for (int i = 0; i < 4; ++i) {
      int cbase = w * 256 + i * 64;
      int chunk = cbase + lane;
      int row = chunk >> 3;
      int lb = (chunk & 7) ^ (row & 7);
      gld16(A + (size_t)(m0 + row) * 512 + k0 + lb * 8, As + cbase * 8);
      gld16(Bt + (size_t)(n0 + row) * 512 + k0 + lb * 8, Bs + cbase * 8);
    }
    __syncthreads();
#pragma unroll
    for (int c = 0; c < 2; ++c) {
      short8 af[4], bf[4];
#pragma unroll
      for (int mt = 0; mt < 4; ++mt)
        af[mt] = *(const short8*)(As + (wy * 64 + mt * 16 + ln) * 64 + (((c * 4 + quad) ^ sw)) * 8);
#pragma unroll
      for (int nt = 0; nt < 4; ++nt)
        bf[nt] = *(const short8*)(Bs + (wx * 64 + nt * 16 + ln) * 64 + (((c * 4 + quad) ^ sw)) * 8);
#pragma unroll
      for (int mt = 0; mt < 4; ++mt)
#pragma unroll
        for (int nt = 0; nt < 4; ++nt)
          acc[mt][nt] = __builtin_amdgcn_mfma_f32_16x16x32_bf16(af[mt], bf[nt], acc[mt][nt], 0, 0, 0);
    }
    __syncthreads();
  }
#pragma unroll
  for (int mt = 0; mt < 4; ++mt)
#pragma unroll
    for (int r = 0; r < 4; ++r) {
      int row = m0 + wy * 64 + mt * 16 + quad * 4 + r;
#pragma unroll
      for (int nt = 0; nt < 4; ++nt) {
        int col = n0 + wx * 64 + nt * 16 + ln;
        epi(row, col, acc[mt][nt][r]);
      }
    }
}

// blocks [0,512): QK proj -> qk[8192][1024]; [512,768): V^T -> vT[512][8192]
__global__ __launch_bounds__(256) void gemm_qkvt_kernel(
    const bf16_t* __restrict__ h_bf, const bf16_t* __restrict__ wqkvT,
    bf16_t* __restrict__ qk, bf16_t* __restrict__ vT) {
  __shared__ __align__(16) bf16_t As[128 * 64];
  __shared__ __align__(16) bf16_t Bs[128 * 64];
  int bx = blockIdx.x;
  if (bx < 512) {
    int m0 = (bx >> 3) * 128, n0 = (bx & 7) * 128;
    gemm_body(h_bf, wqkvT, m0, n0, As, Bs,
              [&](int row, int col, float v) { qk[(size_t)row * 1024 + col] = f2bf(v); });
  } else {
    int local = bx - 512;
    int m0 = (local >> 6) * 128, n0 = (local & 63) * 128;
    gemm_body(wqkvT + 1024 * 512, h_bf, m0, n0, As, Bs,
              [&](int row, int col, float v) { vT[(size_t)row * 8192 + col] = f2bf(v); });
  }
}

// out-proj GEMM + residual (h_bf) epilogue -> o2r bf16 [8192][512]
__global__ __launch_bounds__(256) void gemm_out_kernel(
    const bf16_t* __restrict__ attn, const bf16_t* __restrict__ wfcT,
    const bf16_t* __restrict__ h_bf, bf16_t* __restrict__ o2r) {
  __shared__ __align__(16) bf16_t As[128 * 64];
  __shared__ __align__(16) bf16_t Bs[128 * 64];
  int bx = blockIdx.x;
  int m0 = (bx >> 2) * 128, n0 = (bx & 3) * 128;
  gemm_body(attn, wfcT, m0, n0, As, Bs, [&](int row, int col, float v) {
    size_t o = (size_t)row * 512 + col;
    o2r[o] = f2bf(v + bf2f(h_bf[o]));
  });
}

// ---------------- flash-style causal attention (S^T formulation) ----------------
// qk: [B*T][1024] bf16 (Q | K pre-scaled), vT: [512][8192] bf16
// PV via mfma_16x16x16bf16_1k: S^T C-layout == B-operand layout -> P stays in regs
__global__ __launch_bounds__(256) void attn_kernel(const bf16_t* __restrict__ qk,
                                                   const bf16_t* __restrict__ vT,
                                                   bf16_t* __restrict__ out) {
  __shared__ __align__(16) bf16_t Ks[2][64 * 64];
  __shared__ __align__(16) bf16_t Vs[2][64 * 64];
  const int bx = blockIdx.x;
  const int qt = 31 - (bx >> 5);      // long blocks first
  const int bh = bx & 31;
  const int b = bh >> 3, h = bh & 7;
  const int tid = threadIdx.x;
  const int w = tid >> 6, lane = tid & 63;
  const int ln = lane & 15, quad = lane >> 4;
  const int sw = ln & 7;

  short8 qf0, qf1;
  {
    size_t qrow = ((size_t)b * T_ + qt * 64 + w * 16 + ln) * 1024 + h * 64;
    qf0 = *(const short8*)(qk + qrow + quad * 8);
    qf1 = *(const short8*)(qk + qrow + 32 + quad * 8);
  }
  float4v z = {0.f, 0.f, 0.f, 0.f};
  float4v oacc[4];
#pragma unroll
  for (int i = 0; i < 4; ++i) oacc[i] = z;
  float m_s = -1e30f, l_s = 0.f;

  const bf16_t* kbase = qk + (size_t)b * T_ * 1024 + 512 + h * 64;
  const bf16_t* vbase = vT + (size_t)(h * 64) * 8192 + (size_t)b * T_;

  auto stage = [&](int buf, int kt) {
#pragma unroll
    for (int i = 0; i < 2; ++i) {
      int cbase = w * 128 + i * 64;
      int chunk = cbase + lane;
      int row = chunk >> 3;
      int lb = (chunk & 7) ^ (row & 7);
      gld16(kbase + (size_t)(kt * 64 + row) * 1024 + lb * 8, Ks[buf] + (size_t)cbase * 8);
      gld16(vbase + (size_t)row * 8192 + kt * 64 + lb * 8, Vs[buf] + (size_t)cbase * 8);
    }
  };

  auto compute = [&](const bf16_t* Kc, const bf16_t* Vc, bool mask) {
    float sv[4][4];
#pragma unroll
    for (int mt = 0; mt < 4; ++mt) {
      float4v st = z;
      int row = mt * 16 + ln;
      short8 a0 = *(const short8*)(Kc + row * 64 + ((0 + quad) ^ sw) * 8);
      short8 a1 = *(const short8*)(Kc + row * 64 + ((4 + quad) ^ sw) * 8);
      st = __builtin_amdgcn_mfma_f32_16x16x32_bf16(a0, qf0, st, 0, 0, 0);
      st = __builtin_amdgcn_mfma_f32_16x16x32_bf16(a1, qf1, st, 0, 0, 0);
#pragma unroll
      for (int r = 0; r < 4; ++r) {
        float v = st[r];
        if (mask) {
          int kloc = mt * 16 + quad * 4 + r;
          if (kloc > w * 16 + ln) v = -1e30f;
        }
        sv[mt][r] = v;
      }
    }
    float mx = sv[0][0];
#pragma unroll
    for (int mt = 0; mt < 4; ++mt)
#pragma unroll
      for (int r = 0; r < 4; ++r) mx = fmaxf(mx, sv[mt][r]);
    mx = fmaxf(mx, __shfl_xor(mx, 16, 64));
    mx = fmaxf(mx, __shfl_xor(mx, 32, 64));
    float mn = fmaxf(m_s, mx);
    float alpha = __expf(m_s - mn);
    m_s = mn;
    float rs = 0.f;
#pragma unroll
    for (int mt = 0; mt < 4; ++mt)
#pragma unroll
      for (int r = 0; r < 4; ++r) {
        float p = __expf(sv[mt][r] - mn);
        sv[mt][r] = p;
        rs += p;
      }
    rs += __shfl_xor(rs, 16, 64);
    rs += __shfl_xor(rs, 32, 64);
    l_s = l_s * alpha + rs;
#pragma unroll
    for (int dt = 0; dt < 4; ++dt)
#pragma unroll
      for (int r = 0; r < 4; ++r) oacc[dt][r] *= alpha;
    // pack own 4 exp values per k-subtile -> bf16 B-frag in-register (round half up)
    short4v pf[4];
#pragma unroll
    for (int mt = 0; mt < 4; ++mt) {
      unsigned u0 = __builtin_bit_cast(unsigned, sv[mt][0]) + 0x8000u;
      unsigned u1 = __builtin_bit_cast(unsigned, sv[mt][1]) + 0x8000u;
      unsigned u2 = __builtin_bit_cast(unsigned, sv[mt][2]) + 0x8000u;
      unsigned u3 = __builtin_bit_cast(unsigned, sv[mt][3]) + 0x8000u;
      uint2 pp;
      pp.x = __builtin_amdgcn_perm(u1, u0, 0x07060302u);
      pp.y = __builtin_amdgcn_perm(u3, u2, 0x07060302u);
      pf[mt] = __builtin_bit_cast(short4v, pp);
    }
    // O^T += V^T P : A = V^T frags (m=d in lanes, k=quad*4+j), B = pf
#pragma unroll
    for (int dt = 0; dt < 4; ++dt) {
      int row = dt * 16 + ln;
#pragma unroll
      for (int mt = 0; mt < 4; ++mt) {
        short4v av = *(const short4v*)(Vc + row * 64 + ((2 * mt + (quad >> 1)) ^ sw) * 8 + (quad & 1) * 4);
        oacc[dt] = __builtin_amdgcn_mfma_f32_16x16x16bf16_1k(av, pf[mt], oacc[dt], 0, 0, 0);
      }
    }
  };

  stage(0, 0);
  __syncthreads();
  for (int kt = 0; kt < qt; ++kt) {
    int cur = kt & 1;
    stage(cur ^ 1, kt + 1);
    compute(Ks[cur], Vs[cur], false);
    __syncthreads();
  }
  compute(Ks[qt & 1], Vs[qt & 1], true);

  float inv = 1.0f / l_s;
  size_t obase = ((size_t)b * T_ + qt * 64 + w * 16 + ln) * 512 + h * 64;
#pragma unroll
  for (int dt = 0; dt < 4; ++dt) {
    short4v o4;
#pragma unroll
    for (int r = 0; r < 4; ++r) o4[r] = (short)f2bf(oacc[dt][r] * inv);
    *(short4v*)(out + obase + dt * 16 + quad * 4) = o4;
  }
}

// ---------------- final LN + residual ----------------
__global__ __launch_bounds__(256) void ln2_kernel(
    const bf16_t* __restrict__ o2r, const float* __restrict__ x,
    const float* __restrict__ g, const float* __restrict__ bb,
    float* __restrict__ out) {
  int wave = threadIdx.x >> 6, lane = threadIdx.x & 63;
  int row = blockIdx.x * 4 + wave;
  size_t ro = (size_t)row * D_;
  int c0 = lane * 8;
  short8 ov = *(const short8*)(o2r + ro + c0);
  float t[8];
#pragma unroll
  for (int j = 0; j < 8; ++j) t[j] = bf2f((bf16_t)ov[j]);
  float s = 0.f;
#pragma unroll
  for (int j = 0; j < 8; ++j) s += t[j];
  s = waveReduceSum(s);
  float mu = s * (1.f / 512.f);
  float q = 0.f;
#pragma unroll
  for (int j = 0; j < 8; ++j) { float d = t[j] - mu; q += d * d; }
  q = waveReduceSum(q);
  float rstd = rsqrtf(q * (1.f / 512.f) + 1e-6f);
  float4 x0 = *(const float4*)(x + ro + c0);
  float4 x1 = *(const float4*)(x + ro + c0 + 4);
  float xr[8] = {x0.x, x0.y, x0.z, x0.w, x1.x, x1.y, x1.z, x1.w};
  float o[8];
#pragma unroll
  for (int j = 0; j < 8; ++j) {
    int col = c0 + j;
    o[j] = (t[j] - mu) * rstd * g[col] + bb[col] + xr[j];
  }
  float4 w0 = {o[0], o[1], o[2], o[3]};
  float4 w1 = {o[4], o[5], o[6], o[7]};
  *(float4*)(out + ro + c0) = w0;
  *(float4*)(out + ro + c0 + 4) = w1;
}

// ---------------- launch ----------------
extern "C" void kernel_launch(void* const* d_in, const int* in_sizes, int n_in,
                              void* d_out, int out_size, void* d_ws, size_t ws_size,
                              hipStream_t stream) {
  const float* x   = (const float*)d_in[0];
  const float* g1  = (const float*)d_in[1];
  const float* b1  = (const float*)d_in[2];
  const float* wq  = (const float*)d_in[3];
  const float* wk  = (const float*)d_in[4];
  const float* wv  = (const float*)d_in[5];
  const float* wfc = (const float*)d_in[6];
  const float* g2  = (const float*)d_in[7];
  const float* b2  = (const float*)d_in[8];
  float* out = (float*)d_out;

  char* ws = (char*)d_ws;
  const size_t O_HBF  = 0;          // 8192*512*2  =  8388608
  const size_t O_WQKV = 8388608;    // 1536*512*2  =  1572864
  const size_t O_WFC  = 9961472;    //  512*512*2  =   524288
  const size_t O_QK   = 10485760;   // 8192*1024*2 = 16777216
  const size_t O_VT   = 27262976;   //  512*8192*2 =  8388608
  const size_t O_ATTN = 35651584;   // 8192*512*2  =  8388608
  const size_t O_O2R  = 44040192;   // 8192*512*2  =  8388608
  const size_t WS_NEED = 52428800;
  if (ws_size < WS_NEED) return;

  bf16_t* h_bf  = (bf16_t*)(ws + O_HBF);
  bf16_t* wqkvT = (bf16_t*)(ws + O_WQKV);
  bf16_t* wfcT  = (bf16_t*)(ws + O_WFC);
  bf16_t* qk    = (bf16_t*)(ws + O_QK);
  bf16_t* vT    = (bf16_t*)(ws + O_VT);
  bf16_t* attn  = (bf16_t*)(ws + O_ATTN);
  bf16_t* o2r   = (bf16_t*)(ws + O_O2R);

  pre_kernel<<<dim3(2304), dim3(256), 0, stream>>>(x, g1, b1, wq, wk, wv, wfc,
                                                   h_bf, wqkvT, wfcT);
  gemm_qkvt_kernel<<<dim3(768), dim3(256), 0, stream>>>(h_bf, wqkvT, qk, vT);
  attn_kernel<<<dim3(1024), dim3(256), 0, stream>>>(qk, vT, attn);
  gemm_out_kernel<<<dim3(256), dim3(256), 0, stream>>>(attn, wfcT, h_bf, o2r);
  ln2_kernel<<<dim3(2048), dim3(256), 0, stream>>>(o2r, x, g2, b2, out);
}